// Round 14
// baseline (409.592 us; speedup 1.0000x reference)
//
#include <hip/hip_runtime.h>
#include <cstdint>
#include <cstddef>

#define NEG_SLOPE 0.2f
#define LOG2E 1.44269504f

typedef __attribute__((ext_vector_type(8))) short short8;   // 8 bf16 (4 VGPRs)
typedef __attribute__((ext_vector_type(4))) float f32x4;    // MFMA accumulator
typedef __attribute__((ext_vector_type(2))) float f32x2;    // packed-f32 pair

__device__ __forceinline__ float bflo(unsigned int u) {
    union { unsigned int i; float f; } x; x.i = u << 16; return x.f;
}
__device__ __forceinline__ float bfhi(unsigned int u) {
    union { unsigned int i; float f; } x; x.i = u & 0xFFFF0000u; return x.f;
}
__device__ __forceinline__ unsigned short f2bf(float f) {
    union { float f; unsigned int i; } x;
    x.f = f;
    unsigned int u = x.i;
    return (unsigned short)((u + 0x7FFFu + ((u >> 16) & 1u)) >> 16);   // RNE
}

// =====================================================================
// Weight prep (all 3 layers in one launch):
// Bt[n][k] = bf16([Wl | Wr][k][n]); layer0/1: dout=128, layer2: dout=32.
// =====================================================================
__global__ __launch_bounds__(256) void prep_w_all(
    const float* __restrict__ Wl0, const float* __restrict__ Wr0,
    const float* __restrict__ Wl1, const float* __restrict__ Wr1,
    const float* __restrict__ Wl2, const float* __restrict__ Wr2,
    unsigned short* __restrict__ Bt0, unsigned short* __restrict__ Bt1,
    unsigned short* __restrict__ Bt2)
{
    int idx = blockIdx.x * 256 + threadIdx.x;
    const int SZ = 256 * 128;     // layer0/1 table elems
    const float *Wl, *Wr; unsigned short* Bt; int dout;
    if (idx < SZ)              { Wl = Wl0; Wr = Wr0; Bt = Bt0; dout = 128; }
    else if (idx < 2 * SZ)     { Wl = Wl1; Wr = Wr1; Bt = Bt1; dout = 128; idx -= SZ; }
    else if (idx < 2 * SZ + 64 * 128) { Wl = Wl2; Wr = Wr2; Bt = Bt2; dout = 32; idx -= 2 * SZ; }
    else return;
    int n = idx >> 7, k = idx & 127;
    float v = (n < dout) ? Wl[(size_t)k * dout + n] : Wr[(size_t)k * dout + (n - dout)];
    Bt[idx] = f2bf(v);
}

// =====================================================================
// MFMA GEMM (LDS-staged): XL(bf16) | XR(f32) = A[M x 128] @ Bt^T + bias.
// Block = 128 rows x 64 cols, 256 threads (4 waves); each wave 32 rows
// x 64 cols = 32 MFMAs per staging barrier. LDS 52 KB -> 3 blocks/CU.
// C/D layout: col=lane&15, row=quad*4+reg (validated r11/r12).
// =====================================================================
__global__ __launch_bounds__(256) void gemm_mfma(
    const float* __restrict__ A, int M,
    const unsigned short* __restrict__ Bt,
    const float* __restrict__ bl, const float* __restrict__ br,
    int dout, unsigned short* __restrict__ XL, float* __restrict__ XR)
{
    constexpr int LDA = 136;                       // shorts; pad 128+8
    __shared__ __attribute__((aligned(16))) unsigned short As[128 * LDA];
    __shared__ __attribute__((aligned(16))) unsigned short Bs[64 * LDA];
    const int t  = threadIdx.x;
    const int m0 = blockIdx.x * 128;
    const int n0 = blockIdx.y * 64;

    // ---- stage A (128 x 128 f32 -> bf16), coalesced
#pragma unroll
    for (int i = 0; i < 16; ++i) {
        int c    = t + i * 256;        // [0, 4096)
        int row  = c >> 5;             // 32 float4-chunks per row
        int colc = (c & 31) * 4;
        int gr   = m0 + row;
        float4 v = make_float4(0.f, 0.f, 0.f, 0.f);
        if (gr < M) v = *(const float4*)(A + (size_t)gr * 128 + colc);
        ushort4 o;
        o.x = f2bf(v.x); o.y = f2bf(v.y); o.z = f2bf(v.z); o.w = f2bf(v.w);
        *(ushort4*)(As + row * LDA + colc) = o;
    }
    // ---- stage B (64 x 128 bf16), coalesced
#pragma unroll
    for (int i = 0; i < 4; ++i) {
        int c  = t + i * 256;          // [0, 1024)
        int n  = c >> 4;               // 16 ushort8-chunks per row
        int kc = (c & 15) * 8;
        *(short8*)(Bs + n * LDA + kc) =
            *(const short8*)(Bt + (size_t)(n0 + n) * 128 + kc);
    }
    __syncthreads();

    const int w    = t >> 6;
    const int lane = t & 63;
    const int fr   = lane & 15;
    const int quad = lane >> 4;

    f32x4 acc[2][4] = {};
    const unsigned short* ap0 = As + (w * 32 + fr) * LDA + quad * 8;
    const unsigned short* bp0 = Bs + fr * LDA + quad * 8;
#pragma unroll
    for (int k0 = 0; k0 < 128; k0 += 32) {
        short8 afr0 = *(const short8*)(ap0 + k0);
        short8 afr1 = *(const short8*)(ap0 + 16 * LDA + k0);
#pragma unroll
        for (int j = 0; j < 4; ++j) {
            short8 bfr = *(const short8*)(bp0 + j * 16 * LDA + k0);
            acc[0][j] = __builtin_amdgcn_mfma_f32_16x16x32_bf16(afr0, bfr, acc[0][j], 0, 0, 0);
            acc[1][j] = __builtin_amdgcn_mfma_f32_16x16x32_bf16(afr1, bfr, acc[1][j], 0, 0, 0);
        }
    }

    // ---- epilogue: +bias, split XL(bf16) / XR(f32)
#pragma unroll
    for (int j = 0; j < 4; ++j) {
        int col = n0 + j * 16 + fr;
        float bias = (col < dout) ? bl[col] : br[col - dout];
#pragma unroll
        for (int i = 0; i < 2; ++i) {
#pragma unroll
            for (int r = 0; r < 4; ++r) {
                int row = m0 + w * 32 + i * 16 + quad * 4 + r;
                if (row < M) {
                    float v = acc[i][j][r] + bias;
                    if (col < dout) XL[(size_t)row * dout + col] = f2bf(v);
                    else            XR[(size_t)row * dout + (col - dout)] = v;
                }
            }
        }
    }
}

// =====================================================================
// CSR build over dst: count+rank -> 3-phase device scan -> place (no
// atomics in place; rank captured in count which already pays the RMW).
// =====================================================================
__global__ void count_rank_kernel(const int* __restrict__ dst, int E,
                                  int* __restrict__ cnt, unsigned short* __restrict__ rank)
{
    int e = blockIdx.x * blockDim.x + threadIdx.x;
    if (e < E) {
        int p = atomicAdd(&cnt[dst[e]], 1);
        rank[e] = (unsigned short)p;
    }
}

__global__ __launch_bounds__(256) void scan_partial(
    const int* __restrict__ cnt, int N, int* __restrict__ bsum)
{
    __shared__ int red[4];
    const int t = threadIdx.x;
    const int base = blockIdx.x * 2048;
    int s = 0;
#pragma unroll
    for (int i = 0; i < 8; ++i) {
        int idx = base + t + i * 256;
        if (idx < N) s += cnt[idx];
    }
#pragma unroll
    for (int off = 32; off >= 1; off >>= 1) s += __shfl_xor(s, off);
    if ((t & 63) == 0) red[t >> 6] = s;
    __syncthreads();
    if (t == 0) bsum[blockIdx.x] = red[0] + red[1] + red[2] + red[3];
}

__global__ __launch_bounds__(256) void scan_bsums(
    int* __restrict__ bsum, int nb, int E, int* __restrict__ rowptr, int N)
{
    __shared__ int sh[256];
    const int t = threadIdx.x;
    int v = (t < nb) ? bsum[t] : 0;
    sh[t] = v;
    __syncthreads();
    for (int off = 1; off < 256; off <<= 1) {
        int u = (t >= off) ? sh[t - off] : 0;
        __syncthreads();
        sh[t] += u;
        __syncthreads();
    }
    if (t < nb) bsum[t] = sh[t] - v;   // exclusive prefix
    if (t == 0) rowptr[N] = E;
}

__global__ __launch_bounds__(256) void scan_final(
    const int* __restrict__ cnt, int N, const int* __restrict__ bsum,
    int* __restrict__ rowptr)
{
    __shared__ int sdat[2048];
    __shared__ int tsum[256];
    const int t = threadIdx.x;
    const int base = blockIdx.x * 2048;
#pragma unroll
    for (int i = 0; i < 8; ++i) {
        int idx = base + t + i * 256;
        sdat[t + i * 256] = (idx < N) ? cnt[idx] : 0;
    }
    __syncthreads();
    int vals[8];
    int s = 0;
#pragma unroll
    for (int j = 0; j < 8; ++j) { vals[j] = sdat[t * 8 + j]; s += vals[j]; }
    tsum[t] = s;
    __syncthreads();
    for (int off = 1; off < 256; off <<= 1) {
        int u = (t >= off) ? tsum[t - off] : 0;
        __syncthreads();
        tsum[t] += u;
        __syncthreads();
    }
    int run = bsum[blockIdx.x] + tsum[t] - s;   // exclusive prefix of this chunk
#pragma unroll
    for (int j = 0; j < 8; ++j) { sdat[t * 8 + j] = run; run += vals[j]; }
    __syncthreads();
#pragma unroll
    for (int i = 0; i < 8; ++i) {
        int idx = base + t + i * 256;
        if (idx < N) rowptr[idx] = sdat[t + i * 256];
    }
}

__global__ void place_kernel(const int* __restrict__ src, const int* __restrict__ dst,
                             const unsigned short* __restrict__ rank, int E,
                             const int* __restrict__ rowptr,
                             unsigned short* __restrict__ csr_src)
{
    int e = blockIdx.x * blockDim.x + threadIdx.x;
    if (e < E)
        csr_src[rowptr[dst[e]] + rank[e]] = (unsigned short)src[e];
}

// =====================================================================
// Fused GATv2 edge phase — bf16 table, 4 channels/lane, PACKED f32:
//   float2 ext-vectors + __builtin_elementwise_fma/abs lower to
//   <2 x float> IR -> v_pk_{add,mul,fma}_f32 on gfx950, halving the
//   per-edge f32 chain. Dot uses leaky(s) = 0.6s + 0.4|s| (no packed
//   max exists). Plain-sum exp2-domain softmax. One wave per dst node
//   (4 nodes / 256-thread block), no LDS, no barriers.
// =====================================================================
template<int H>
__global__ __launch_bounds__(256, 4) void gat_fused(
    const unsigned short* __restrict__ xl, const float* __restrict__ xr,
    const int* __restrict__ rowptr, const unsigned short* __restrict__ csr_src,
    const float* __restrict__ att, const float* __restrict__ bias,
    float* __restrict__ hout, int hstride, int N)
{
    constexpr int HC  = 32 * H;
    constexpr int LPE = HC / 4;      // lanes per edge (H=4: 32, H=1: 8)
    constexpr int EPW = 64 / LPE;    // edge slots per wave (2 / 8)
    const int node = blockIdx.x * 4 + (threadIdx.x >> 6);
    if (node >= N) return;
    const int lane = threadIdx.x & 63;
    const int q    = lane % LPE;
    const int slot = lane / LPE;
    const int rs   = rowptr[node];
    const int re   = rowptr[node + 1];

    const unsigned short* __restrict__ xlb = xl + 4 * q;

    f32x2 xr01, xr23, a6_01, a6_23, a4_01, a4_23;
    {
        const float4 xv = *(const float4*)(xr + (size_t)node * HC + 4 * q);
        const float4 av = *(const float4*)(att + 4 * q);
        xr01.x = xv.x; xr01.y = xv.y; xr23.x = xv.z; xr23.y = xv.w;
        a6_01.x = av.x * (0.6f * LOG2E); a6_01.y = av.y * (0.6f * LOG2E);
        a6_23.x = av.z * (0.6f * LOG2E); a6_23.y = av.w * (0.6f * LOG2E);
        a4_01.x = av.x * (0.4f * LOG2E); a4_01.y = av.y * (0.4f * LOG2E);
        a4_23.x = av.z * (0.4f * LOG2E); a4_23.y = av.w * (0.4f * LOG2E);
    }

    float l = 0.f;
    f32x2 ac01 = {0.f, 0.f}, ac23 = {0.f, 0.f};

    struct V2 { f32x2 v01, v23; };
    auto ld4 = [&](int s) -> V2 {
        uint2 u = *(const uint2*)(xlb + (size_t)s * HC);
        V2 r;
        r.v01.x = bflo(u.x); r.v01.y = bfhi(u.x);
        r.v23.x = bflo(u.y); r.v23.y = bfhi(u.y);
        return r;
    };

    auto edge_w = [&](const V2& v) -> float {   // exp2(att . leakyrelu(v+xri) * log2e)
        f32x2 s01 = v.v01 + xr01;
        f32x2 s23 = v.v23 + xr23;
        f32x2 t01 = __builtin_elementwise_abs(s01);
        f32x2 t23 = __builtin_elementwise_abs(s23);
        f32x2 p2 = s01 * a6_01;
        p2 = __builtin_elementwise_fma(s23, a6_23, p2);
        p2 = __builtin_elementwise_fma(t01, a4_01, p2);
        p2 = __builtin_elementwise_fma(t23, a4_23, p2);
        float p = p2.x + p2.y;
        p += __shfl_xor(p, 1);
        p += __shfl_xor(p, 2);
        p += __shfl_xor(p, 4);
        return exp2f(p);
    };

    // ---- self-loop (src = dst = node), slot 0 only
    if (slot == 0) {
        V2 v = ld4(node);
        float w = edge_w(v);
        l = w;
        f32x2 wv; wv.x = w; wv.y = w;
        ac01 = wv * v.v01;
        ac23 = wv * v.v23;
    }

    // ---- incoming edges, strided per slot, unrolled x2 (no predication)
    int k = rs + slot;
    for (; k + EPW < re; k += 2 * EPW) {
        int s0 = csr_src[k];
        int s1 = csr_src[k + EPW];
        V2 v0 = ld4(s0);
        V2 v1 = ld4(s1);
        float w0 = edge_w(v0);
        float w1 = edge_w(v1);
        l += w0 + w1;
        f32x2 w0v; w0v.x = w0; w0v.y = w0;
        f32x2 w1v; w1v.x = w1; w1v.y = w1;
        ac01 = __builtin_elementwise_fma(w0v, v0.v01, __builtin_elementwise_fma(w1v, v1.v01, ac01));
        ac23 = __builtin_elementwise_fma(w0v, v0.v23, __builtin_elementwise_fma(w1v, v1.v23, ac23));
    }
    if (k < re) {
        int s0 = csr_src[k];
        V2 v0 = ld4(s0);
        float w0 = edge_w(v0);
        l += w0;
        f32x2 w0v; w0v.x = w0; w0v.y = w0;
        ac01 = __builtin_elementwise_fma(w0v, v0.v01, ac01);
        ac23 = __builtin_elementwise_fma(w0v, v0.v23, ac23);
    }

    // ---- merge edge slots: plain sums
#pragma unroll
    for (int mask = LPE; mask < 64; mask <<= 1) {
        l      += __shfl_xor(l, mask);
        ac01.x += __shfl_xor(ac01.x, mask);
        ac01.y += __shfl_xor(ac01.y, mask);
        ac23.x += __shfl_xor(ac23.x, mask);
        ac23.y += __shfl_xor(ac23.y, mask);
    }

    if (lane < LPE) {
        const float4 bi = *(const float4*)(bias + 4 * q);
        float inv = 1.f / (l + 1e-16f);
        float4 o;
        o.x = ac01.x * inv + bi.x;
        o.y = ac01.y * inv + bi.y;
        o.z = ac23.x * inv + bi.z;
        o.w = ac23.y * inv + bi.w;
        o.x = (o.x > 0.f) ? o.x : expm1f(o.x);
        o.y = (o.y > 0.f) ? o.y : expm1f(o.y);
        o.z = (o.z > 0.f) ? o.z : expm1f(o.z);
        o.w = (o.w > 0.f) ? o.w : expm1f(o.w);
        *(float4*)(hout + (size_t)node * hstride + 4 * q) = o;
    }
}

// =====================================================================
// Fused mean-pool + MLP head. One block per graph; batch is SORTED so
// graph b's nodes are rows [lower_bound(b), lower_bound(b+1)).
// =====================================================================
__global__ __launch_bounds__(128) void pool_head_kernel(
    const float* __restrict__ h, int hstride,
    const int* __restrict__ batch, int N,
    const float* __restrict__ meta,
    const float* __restrict__ Wh1, const float* __restrict__ bh1,
    const float* __restrict__ Wh2, const float* __restrict__ bh2,
    float* __restrict__ out)
{
    const int b = blockIdx.x;
    const int t = threadIdx.x;
    __shared__ float s[128];
    __shared__ float z[44];

    int lo = 0, hi = N;
    while (lo < hi) { int mid = (lo + hi) >> 1; if (batch[mid] < b) lo = mid + 1; else hi = mid; }
    int lo2 = lo, hi2 = N;
    while (lo2 < hi2) { int mid = (lo2 + hi2) >> 1; if (batch[mid] < b + 1) lo2 = mid + 1; else hi2 = mid; }
    const int start = lo, end = lo2;

    const int c = t & 31, r = t >> 5;     // 4 rows x 32 channels in flight
    float acc = 0.f;
    for (int row = start + r; row < end; row += 4)
        acc += h[(size_t)row * hstride + c];
    s[t] = acc;
    __syncthreads();
    if (t < 32) {
        float sum = s[t] + s[t + 32] + s[t + 64] + s[t + 96];
        z[t] = sum / fmaxf((float)(end - start), 1.0f);
    } else if (t < 44) {
        z[t] = meta[(size_t)b * 12 + (t - 32)];
    }
    __syncthreads();
    if (t < 32) {
        float hj = bh1[t];
#pragma unroll
        for (int k = 0; k < 44; ++k)
            hj = fmaf(z[k], Wh1[k * 32 + t], hj);
        hj = fmaxf(hj, 0.f);
        float p = hj * Wh2[t];
#pragma unroll
        for (int off = 16; off >= 1; off >>= 1)
            p += __shfl_xor(p, off, 32);
        if (t == 0) out[b] = p + bh2[0];
    }
}

// =====================================================================
extern "C" void kernel_launch(void* const* d_in, const int* in_sizes, int n_in,
                              void* d_out, int out_size, void* d_ws, size_t ws_size,
                              hipStream_t stream)
{
    const float* x     = (const float*)d_in[0];
    const int*   ei    = (const int*)d_in[1];
    const int*   batch = (const int*)d_in[2];
    const float* meta  = (const float*)d_in[3];
    const float* Wl[3]  = {(const float*)d_in[4],  (const float*)d_in[10], (const float*)d_in[16]};
    const float* bl[3]  = {(const float*)d_in[5],  (const float*)d_in[11], (const float*)d_in[17]};
    const float* Wr[3]  = {(const float*)d_in[6],  (const float*)d_in[12], (const float*)d_in[18]};
    const float* br[3]  = {(const float*)d_in[7],  (const float*)d_in[13], (const float*)d_in[19]};
    const float* att[3] = {(const float*)d_in[8],  (const float*)d_in[14], (const float*)d_in[20]};
    const float* bb[3]  = {(const float*)d_in[9],  (const float*)d_in[15], (const float*)d_in[21]};
    const float* Wh1 = (const float*)d_in[22];
    const float* bh1 = (const float*)d_in[23];
    const float* Wh2 = (const float*)d_in[24];
    const float* bh2 = (const float*)d_in[25];
    float* out = (float*)d_out;

    const int N  = in_sizes[0] / 128;
    const int E  = in_sizes[1] / 2;
    const int B  = in_sizes[3] / 12;
    const int NB = (N + 2047) / 2048;   // scan tiles (<= 256)

    char* wsp = (char*)d_ws;
    size_t off_ = 0;
    auto alloc = [&](size_t bytes) {
        char* p = wsp + off_;
        off_ = (off_ + bytes + 255) & ~(size_t)255;
        return p;
    };
    unsigned short* xlbuf = (unsigned short*)alloc((size_t)N * 128 * 2);  // bf16 gather table
    float* xrbuf   = (float*)alloc((size_t)N * 128 * 4);  // xr table (f32)
    float* hbuf    = (float*)alloc((size_t)N * 128 * 4);  // layer output (ELU'd)
    int*   cnt     = (int*)alloc((size_t)N * 4);
    int*   rowptr  = (int*)alloc((size_t)(N + 1) * 4);
    unsigned short* rank    = (unsigned short*)alloc((size_t)E * 2);  // rank within dst bucket
    unsigned short* csr_src = (unsigned short*)alloc((size_t)E * 2);  // src < 65536
    unsigned short* Bt0     = (unsigned short*)alloc((size_t)256 * 128 * 2);
    unsigned short* Bt1     = (unsigned short*)alloc((size_t)256 * 128 * 2);
    unsigned short* Bt2     = (unsigned short*)alloc((size_t)64 * 128 * 2);
    int*   bsum    = (int*)alloc((size_t)256 * 4);

    const int* srcI = ei;
    const int* dstI = ei + E;

    // ---- weight prep (independent of everything else)
    prep_w_all<<<(2 * 256 * 128 + 64 * 128 + 255) / 256, 256, 0, stream>>>(
        Wl[0], Wr[0], Wl[1], Wr[1], Wl[2], Wr[2], Bt0, Bt1, Bt2);

    // ---- CSR over dst (real edges; self-loops handled inside gat_fused)
    hipMemsetAsync(cnt, 0, (size_t)N * 4, stream);
    count_rank_kernel<<<(E + 255) / 256, 256, 0, stream>>>(dstI, E, cnt, rank);
    scan_partial<<<NB, 256, 0, stream>>>(cnt, N, bsum);
    scan_bsums<<<1, 256, 0, stream>>>(bsum, NB, E, rowptr, N);
    scan_final<<<NB, 256, 0, stream>>>(cnt, N, bsum, rowptr);
    place_kernel<<<(E + 255) / 256, 256, 0, stream>>>(srcI, dstI, rank, E, rowptr, csr_src);

    const int GB = (N + 3) / 4;      // gat_fused blocks (4 nodes / 256-thread block)
    const int MB = (N + 127) / 128;  // gemm row-tiles (BM=128)

    // ---- layer 0 (din=128, H=4, C=32, concat)
    {
        gemm_mfma<<<dim3(MB, 4), 256, 0, stream>>>(x, N, Bt0, bl[0], br[0], 128, xlbuf, xrbuf);
        gat_fused<4><<<GB, 256, 0, stream>>>(xlbuf, xrbuf, rowptr, csr_src, att[0], bb[0], hbuf, 128, N);
    }
    // ---- layer 1
    {
        gemm_mfma<<<dim3(MB, 4), 256, 0, stream>>>(hbuf, N, Bt1, bl[1], br[1], 128, xlbuf, xrbuf);
        gat_fused<4><<<GB, 256, 0, stream>>>(xlbuf, xrbuf, rowptr, csr_src, att[1], bb[1], hbuf, 128, N);
    }
    // ---- layer 2 (H=1, concat=False -> mean over 1 head = identity)
    {
        gemm_mfma<<<dim3(MB, 1), 256, 0, stream>>>(hbuf, N, Bt2, bl[2], br[2], 32, xlbuf, xrbuf);
        gat_fused<1><<<GB, 256, 0, stream>>>(xlbuf, xrbuf, rowptr, csr_src, att[2], bb[2], hbuf, 32, N);
    }
    // ---- fused global mean pool + head (batch sorted -> binary search, no atomics)
    pool_head_kernel<<<B, 128, 0, stream>>>(hbuf, 32, batch, N, meta, Wh1, bh1, Wh2, bh2, out);
}

// Round 15
// 385.313 us; speedup vs baseline: 1.0630x; 1.0630x over previous
//
#include <hip/hip_runtime.h>
#include <cstdint>
#include <cstddef>

#define NEG_SLOPE 0.2f
#define LOG2E 1.44269504f

typedef __attribute__((ext_vector_type(8))) short short8;   // 8 bf16 (4 VGPRs)
typedef __attribute__((ext_vector_type(4))) float f32x4;    // MFMA accumulator

__device__ __forceinline__ float bf2f(unsigned short u) {
    union { unsigned int i; float f; } x; x.i = ((unsigned int)u) << 16; return x.f;
}
__device__ __forceinline__ unsigned short f2bf(float f) {
    union { float f; unsigned int i; } x;
    x.f = f;
    unsigned int u = x.i;
    return (unsigned short)((u + 0x7FFFu + ((u >> 16) & 1u)) >> 16);   // RNE
}

// =====================================================================
// Weight prep (all 3 layers in one launch):
// Bt[n][k] = bf16([Wl | Wr][k][n]); layer0/1: dout=128, layer2: dout=32.
// =====================================================================
__global__ __launch_bounds__(256) void prep_w_all(
    const float* __restrict__ Wl0, const float* __restrict__ Wr0,
    const float* __restrict__ Wl1, const float* __restrict__ Wr1,
    const float* __restrict__ Wl2, const float* __restrict__ Wr2,
    unsigned short* __restrict__ Bt0, unsigned short* __restrict__ Bt1,
    unsigned short* __restrict__ Bt2)
{
    int idx = blockIdx.x * 256 + threadIdx.x;
    const int SZ = 256 * 128;     // layer0/1 table elems
    const float *Wl, *Wr; unsigned short* Bt; int dout;
    if (idx < SZ)              { Wl = Wl0; Wr = Wr0; Bt = Bt0; dout = 128; }
    else if (idx < 2 * SZ)     { Wl = Wl1; Wr = Wr1; Bt = Bt1; dout = 128; idx -= SZ; }
    else if (idx < 2 * SZ + 64 * 128) { Wl = Wl2; Wr = Wr2; Bt = Bt2; dout = 32; idx -= 2 * SZ; }
    else return;
    int n = idx >> 7, k = idx & 127;
    float v = (n < dout) ? Wl[(size_t)k * dout + n] : Wr[(size_t)k * dout + (n - dout)];
    Bt[idx] = f2bf(v);
}

// =====================================================================
// MFMA GEMM (LDS-staged): XL(bf16) | XR(bf16) = A[M x 128] @ Bt^T + b.
// Block = 64 rows x BN cols, 256 threads (4 waves); wave w owns rows
// [w*16, w*16+16) x all BN cols (NT = BN/16 n-tiles, 4 k-steps).
// A staged into LDS as bf16 (direct copy if ABF16, f32->bf16 else).
// LDS stride 136 shorts -> fragment ds_read_b128 2-way aliased (free).
// C/D layout: col=lane&15, row=quad*4+reg (validated r11/r12).
// =====================================================================
template<int BN, bool ABF16>
__global__ __launch_bounds__(256) void gemm_mfma(
    const void* __restrict__ Avoid, int M,
    const unsigned short* __restrict__ Bt,
    const float* __restrict__ bl, const float* __restrict__ br,
    int dout, unsigned short* __restrict__ XL, unsigned short* __restrict__ XR)
{
    constexpr int LDA = 136;                       // shorts; pad 128+8
    constexpr int NT  = BN / 16;
    __shared__ __attribute__((aligned(16))) unsigned short As[64 * LDA];
    __shared__ __attribute__((aligned(16))) unsigned short Bs[BN * LDA];
    const int t  = threadIdx.x;
    const int m0 = blockIdx.x * 64;
    const int n0 = blockIdx.y * BN;

    // ---- stage A (64 x 128 -> bf16 LDS), coalesced
    if (ABF16) {
        const unsigned short* A = (const unsigned short*)Avoid;
#pragma unroll
        for (int i = 0; i < 8; ++i) {
            int c   = t + i * 256;         // ushort4 chunks, [0, 2048)
            int row = c >> 5;              // 32 chunks per row
            int col = (c & 31) * 4;
            int gr  = m0 + row;
            ushort4 v = make_ushort4(0, 0, 0, 0);
            if (gr < M) v = *(const ushort4*)(A + (size_t)gr * 128 + col);
            *(ushort4*)(As + row * LDA + col) = v;
        }
    } else {
        const float* A = (const float*)Avoid;
#pragma unroll
        for (int i = 0; i < 8; ++i) {
            int c   = t + i * 256;         // float4 chunks, [0, 2048)
            int row = c >> 5;
            int col = (c & 31) * 4;
            int gr  = m0 + row;
            float4 v = make_float4(0.f, 0.f, 0.f, 0.f);
            if (gr < M) v = *(const float4*)(A + (size_t)gr * 128 + col);
            ushort4 o;
            o.x = f2bf(v.x); o.y = f2bf(v.y); o.z = f2bf(v.z); o.w = f2bf(v.w);
            *(ushort4*)(As + row * LDA + col) = o;
        }
    }
    // ---- stage B (BN x 128 bf16), coalesced
#pragma unroll
    for (int i = 0; i < BN / 16; ++i) {
        int c  = t + i * 256;              // short8 chunks
        int n  = c >> 4;                   // 16 chunks per row
        int kc = (c & 15) * 8;
        *(short8*)(Bs + n * LDA + kc) =
            *(const short8*)(Bt + (size_t)(n0 + n) * 128 + kc);
    }
    __syncthreads();

    const int w    = t >> 6;
    const int lane = t & 63;
    const int fr   = lane & 15;
    const int quad = lane >> 4;

    f32x4 acc[NT] = {};
    const unsigned short* ap = As + (w * 16 + fr) * LDA + quad * 8;
    const unsigned short* bp = Bs + fr * LDA + quad * 8;
#pragma unroll
    for (int k0 = 0; k0 < 128; k0 += 32) {
        short8 afr = *(const short8*)(ap + k0);
#pragma unroll
        for (int j = 0; j < NT; ++j) {
            short8 bfr = *(const short8*)(bp + j * 16 * LDA + k0);
            acc[j] = __builtin_amdgcn_mfma_f32_16x16x32_bf16(afr, bfr, acc[j], 0, 0, 0);
        }
    }

    // ---- epilogue: +bias, bf16 stores into XL | XR
#pragma unroll
    for (int j = 0; j < NT; ++j) {
        int col = n0 + j * 16 + fr;
        float bias = (col < dout) ? bl[col] : br[col - dout];
#pragma unroll
        for (int r = 0; r < 4; ++r) {
            int row = m0 + w * 16 + quad * 4 + r;
            if (row < M) {
                unsigned short o = f2bf(acc[j][r] + bias);
                if (col < dout) XL[(size_t)row * dout + col] = o;
                else            XR[(size_t)row * dout + (col - dout)] = o;
            }
        }
    }
}

// =====================================================================
// CSR build over dst: count+rank -> 3-phase device scan -> place (no
// atomics in place; rank captured in count which already pays the RMW).
// =====================================================================
__global__ void count_rank_kernel(const int* __restrict__ dst, int E,
                                  int* __restrict__ cnt, unsigned short* __restrict__ rank)
{
    int e = blockIdx.x * blockDim.x + threadIdx.x;
    if (e < E) {
        int p = atomicAdd(&cnt[dst[e]], 1);
        rank[e] = (unsigned short)p;
    }
}

__global__ __launch_bounds__(256) void scan_partial(
    const int* __restrict__ cnt, int N, int* __restrict__ bsum)
{
    __shared__ int red[4];
    const int t = threadIdx.x;
    const int base = blockIdx.x * 2048;
    int s = 0;
#pragma unroll
    for (int i = 0; i < 8; ++i) {
        int idx = base + t + i * 256;
        if (idx < N) s += cnt[idx];
    }
#pragma unroll
    for (int off = 32; off >= 1; off >>= 1) s += __shfl_xor(s, off);
    if ((t & 63) == 0) red[t >> 6] = s;
    __syncthreads();
    if (t == 0) bsum[blockIdx.x] = red[0] + red[1] + red[2] + red[3];
}

__global__ __launch_bounds__(256) void scan_bsums(
    int* __restrict__ bsum, int nb, int E, int* __restrict__ rowptr, int N)
{
    __shared__ int sh[256];
    const int t = threadIdx.x;
    int v = (t < nb) ? bsum[t] : 0;
    sh[t] = v;
    __syncthreads();
    for (int off = 1; off < 256; off <<= 1) {
        int u = (t >= off) ? sh[t - off] : 0;
        __syncthreads();
        sh[t] += u;
        __syncthreads();
    }
    if (t < nb) bsum[t] = sh[t] - v;   // exclusive prefix
    if (t == 0) rowptr[N] = E;
}

__global__ __launch_bounds__(256) void scan_final(
    const int* __restrict__ cnt, int N, const int* __restrict__ bsum,
    int* __restrict__ rowptr)
{
    __shared__ int sdat[2048];
    __shared__ int tsum[256];
    const int t = threadIdx.x;
    const int base = blockIdx.x * 2048;
#pragma unroll
    for (int i = 0; i < 8; ++i) {
        int idx = base + t + i * 256;
        sdat[t + i * 256] = (idx < N) ? cnt[idx] : 0;
    }
    __syncthreads();
    int vals[8];
    int s = 0;
#pragma unroll
    for (int j = 0; j < 8; ++j) { vals[j] = sdat[t * 8 + j]; s += vals[j]; }
    tsum[t] = s;
    __syncthreads();
    for (int off = 1; off < 256; off <<= 1) {
        int u = (t >= off) ? tsum[t - off] : 0;
        __syncthreads();
        tsum[t] += u;
        __syncthreads();
    }
    int run = bsum[blockIdx.x] + tsum[t] - s;   // exclusive prefix of this chunk
#pragma unroll
    for (int j = 0; j < 8; ++j) { sdat[t * 8 + j] = run; run += vals[j]; }
    __syncthreads();
#pragma unroll
    for (int i = 0; i < 8; ++i) {
        int idx = base + t + i * 256;
        if (idx < N) rowptr[idx] = sdat[t + i * 256];
    }
}

__global__ void place_kernel(const int* __restrict__ src, const int* __restrict__ dst,
                             const unsigned short* __restrict__ rank, int E,
                             const int* __restrict__ rowptr,
                             unsigned short* __restrict__ csr_src)
{
    int e = blockIdx.x * blockDim.x + threadIdx.x;
    if (e < E)
        csr_src[rowptr[dst[e]] + rank[e]] = (unsigned short)src[e];
}

// =====================================================================
// Fused GATv2 edge phase — bf16 xl/xr tables, bf16 output, 4 ch/lane
// (r12-measured-best inner loop): LPE = HC/4 lanes per edge; EPW =
// 64/LPE slots per wave. One wave per dst node (4 nodes / 256-thread
// block), no LDS, no barriers. Plain-sum exp2-domain softmax (logits
// O(15): no f32 overflow risk).
// =====================================================================
template<int H>
__global__ __launch_bounds__(256, 4) void gat_fused(
    const unsigned short* __restrict__ xl, const unsigned short* __restrict__ xr,
    const int* __restrict__ rowptr, const unsigned short* __restrict__ csr_src,
    const float* __restrict__ att, const float* __restrict__ bias,
    unsigned short* __restrict__ hout, int hstride, int N)
{
    constexpr int HC  = 32 * H;
    constexpr int LPE = HC / 4;      // lanes per edge (H=4: 32, H=1: 8)
    constexpr int EPW = 64 / LPE;    // edge slots per wave (2 / 8)
    const int node = blockIdx.x * 4 + (threadIdx.x >> 6);
    if (node >= N) return;
    const int lane = threadIdx.x & 63;
    const int q    = lane % LPE;
    const int slot = lane / LPE;
    const int rs   = rowptr[node];
    const int re   = rowptr[node + 1];

    const unsigned short* __restrict__ xlb = xl + 4 * q;
    float4 xri;
    {
        ushort4 u = *(const ushort4*)(xr + (size_t)node * HC + 4 * q);
        xri.x = bf2f(u.x); xri.y = bf2f(u.y); xri.z = bf2f(u.z); xri.w = bf2f(u.w);
    }
    float4 af = *(const float4*)(att + 4 * q);
    af.x *= LOG2E; af.y *= LOG2E; af.z *= LOG2E; af.w *= LOG2E;   // exp2 domain

    float l = 0.f;
    float4 acc = make_float4(0.f, 0.f, 0.f, 0.f);

    auto ld4 = [&](int s) -> float4 {
        ushort4 u = *(const ushort4*)(xlb + (size_t)s * HC);
        float4 v;
        v.x = bf2f(u.x); v.y = bf2f(u.y); v.z = bf2f(u.z); v.w = bf2f(u.w);
        return v;
    };

    auto edge_w = [&](const float4& v) -> float {   // exp2(att . leakyrelu(v+xri))
        float sx = v.x + xri.x, sy = v.y + xri.y, sz = v.z + xri.z, sw = v.w + xri.w;
        sx = fmaxf(sx, NEG_SLOPE * sx);
        sy = fmaxf(sy, NEG_SLOPE * sy);
        sz = fmaxf(sz, NEG_SLOPE * sz);
        sw = fmaxf(sw, NEG_SLOPE * sw);
        float p = af.x * sx;
        p = fmaf(af.y, sy, p);
        p = fmaf(af.z, sz, p);
        p = fmaf(af.w, sw, p);
        p += __shfl_xor(p, 1);
        p += __shfl_xor(p, 2);
        p += __shfl_xor(p, 4);
        return exp2f(p);
    };

    // ---- self-loop (src = dst = node), slot 0 only
    if (slot == 0) {
        float4 v = ld4(node);
        float w = edge_w(v);
        l = w;
        acc.x = w * v.x; acc.y = w * v.y; acc.z = w * v.z; acc.w = w * v.w;
    }

    // ---- incoming edges, strided per slot, unrolled x2 (no predication)
    int k = rs + slot;
    for (; k + EPW < re; k += 2 * EPW) {
        int s0 = csr_src[k];
        int s1 = csr_src[k + EPW];
        float4 v0 = ld4(s0);
        float4 v1 = ld4(s1);
        float w0 = edge_w(v0);
        float w1 = edge_w(v1);
        l += w0 + w1;
        acc.x = fmaf(w0, v0.x, fmaf(w1, v1.x, acc.x));
        acc.y = fmaf(w0, v0.y, fmaf(w1, v1.y, acc.y));
        acc.z = fmaf(w0, v0.z, fmaf(w1, v1.z, acc.z));
        acc.w = fmaf(w0, v0.w, fmaf(w1, v1.w, acc.w));
    }
    if (k < re) {
        int s0 = csr_src[k];
        float4 v0 = ld4(s0);
        float w0 = edge_w(v0);
        l += w0;
        acc.x = fmaf(w0, v0.x, acc.x);
        acc.y = fmaf(w0, v0.y, acc.y);
        acc.z = fmaf(w0, v0.z, acc.z);
        acc.w = fmaf(w0, v0.w, acc.w);
    }

    // ---- merge edge slots: plain sums
#pragma unroll
    for (int mask = LPE; mask < 64; mask <<= 1) {
        l     += __shfl_xor(l, mask);
        acc.x += __shfl_xor(acc.x, mask);
        acc.y += __shfl_xor(acc.y, mask);
        acc.z += __shfl_xor(acc.z, mask);
        acc.w += __shfl_xor(acc.w, mask);
    }

    if (lane < LPE) {
        const float4 bi = *(const float4*)(bias + 4 * q);
        float inv = 1.f / (l + 1e-16f);
        float4 o;
        o.x = acc.x * inv + bi.x;
        o.y = acc.y * inv + bi.y;
        o.z = acc.z * inv + bi.z;
        o.w = acc.w * inv + bi.w;
        o.x = (o.x > 0.f) ? o.x : expm1f(o.x);
        o.y = (o.y > 0.f) ? o.y : expm1f(o.y);
        o.z = (o.z > 0.f) ? o.z : expm1f(o.z);
        o.w = (o.w > 0.f) ? o.w : expm1f(o.w);
        ushort4 ob;
        ob.x = f2bf(o.x); ob.y = f2bf(o.y); ob.z = f2bf(o.z); ob.w = f2bf(o.w);
        *(ushort4*)(hout + (size_t)node * hstride + 4 * q) = ob;
    }
}

// =====================================================================
// Fused mean-pool + MLP head (h is bf16). One block per graph; batch is
// SORTED so graph b's nodes are rows [lower_bound(b), lower_bound(b+1)).
// =====================================================================
__global__ __launch_bounds__(128) void pool_head_kernel(
    const unsigned short* __restrict__ h, int hstride,
    const int* __restrict__ batch, int N,
    const float* __restrict__ meta,
    const float* __restrict__ Wh1, const float* __restrict__ bh1,
    const float* __restrict__ Wh2, const float* __restrict__ bh2,
    float* __restrict__ out)
{
    const int b = blockIdx.x;
    const int t = threadIdx.x;
    __shared__ float s[128];
    __shared__ float z[44];

    int lo = 0, hi = N;
    while (lo < hi) { int mid = (lo + hi) >> 1; if (batch[mid] < b) lo = mid + 1; else hi = mid; }
    int lo2 = lo, hi2 = N;
    while (lo2 < hi2) { int mid = (lo2 + hi2) >> 1; if (batch[mid] < b + 1) lo2 = mid + 1; else hi2 = mid; }
    const int start = lo, end = lo2;

    const int c = t & 31, r = t >> 5;     // 4 rows x 32 channels in flight
    float acc = 0.f;
    for (int row = start + r; row < end; row += 4)
        acc += bf2f(h[(size_t)row * hstride + c]);
    s[t] = acc;
    __syncthreads();
    if (t < 32) {
        float sum = s[t] + s[t + 32] + s[t + 64] + s[t + 96];
        z[t] = sum / fmaxf((float)(end - start), 1.0f);
    } else if (t < 44) {
        z[t] = meta[(size_t)b * 12 + (t - 32)];
    }
    __syncthreads();
    if (t < 32) {
        float hj = bh1[t];
#pragma unroll
        for (int k = 0; k < 44; ++k)
            hj = fmaf(z[k], Wh1[k * 32 + t], hj);
        hj = fmaxf(hj, 0.f);
        float p = hj * Wh2[t];
#pragma unroll
        for (int off = 16; off >= 1; off >>= 1)
            p += __shfl_xor(p, off, 32);
        if (t == 0) out[b] = p + bh2[0];
    }
}

// =====================================================================
extern "C" void kernel_launch(void* const* d_in, const int* in_sizes, int n_in,
                              void* d_out, int out_size, void* d_ws, size_t ws_size,
                              hipStream_t stream)
{
    const float* x     = (const float*)d_in[0];
    const int*   ei    = (const int*)d_in[1];
    const int*   batch = (const int*)d_in[2];
    const float* meta  = (const float*)d_in[3];
    const float* Wl[3]  = {(const float*)d_in[4],  (const float*)d_in[10], (const float*)d_in[16]};
    const float* bl[3]  = {(const float*)d_in[5],  (const float*)d_in[11], (const float*)d_in[17]};
    const float* Wr[3]  = {(const float*)d_in[6],  (const float*)d_in[12], (const float*)d_in[18]};
    const float* br[3]  = {(const float*)d_in[7],  (const float*)d_in[13], (const float*)d_in[19]};
    const float* att[3] = {(const float*)d_in[8],  (const float*)d_in[14], (const float*)d_in[20]};
    const float* bb[3]  = {(const float*)d_in[9],  (const float*)d_in[15], (const float*)d_in[21]};
    const float* Wh1 = (const float*)d_in[22];
    const float* bh1 = (const float*)d_in[23];
    const float* Wh2 = (const float*)d_in[24];
    const float* bh2 = (const float*)d_in[25];
    float* out = (float*)d_out;

    const int N  = in_sizes[0] / 128;
    const int E  = in_sizes[1] / 2;
    const int B  = in_sizes[3] / 12;
    const int NB = (N + 2047) / 2048;   // scan tiles (<= 256)

    char* wsp = (char*)d_ws;
    size_t off_ = 0;
    auto alloc = [&](size_t bytes) {
        char* p = wsp + off_;
        off_ = (off_ + bytes + 255) & ~(size_t)255;
        return p;
    };
    unsigned short* xlbuf = (unsigned short*)alloc((size_t)N * 128 * 2);  // bf16 gather table
    unsigned short* xrbuf = (unsigned short*)alloc((size_t)N * 128 * 2);  // bf16 xr table
    unsigned short* hbuf  = (unsigned short*)alloc((size_t)N * 128 * 2);  // bf16 layer output
    int*   cnt     = (int*)alloc((size_t)N * 4);
    int*   rowptr  = (int*)alloc((size_t)(N + 1) * 4);
    unsigned short* rank    = (unsigned short*)alloc((size_t)E * 2);  // rank within dst bucket
    unsigned short* csr_src = (unsigned short*)alloc((size_t)E * 2);  // src < 65536
    unsigned short* Bt0     = (unsigned short*)alloc((size_t)256 * 128 * 2);
    unsigned short* Bt1     = (unsigned short*)alloc((size_t)256 * 128 * 2);
    unsigned short* Bt2     = (unsigned short*)alloc((size_t)64 * 128 * 2);
    int*   bsum    = (int*)alloc((size_t)256 * 4);

    const int* srcI = ei;
    const int* dstI = ei + E;

    // ---- weight prep (independent of everything else)
    prep_w_all<<<(2 * 256 * 128 + 64 * 128 + 255) / 256, 256, 0, stream>>>(
        Wl[0], Wr[0], Wl[1], Wr[1], Wl[2], Wr[2], Bt0, Bt1, Bt2);

    // ---- CSR over dst (real edges; self-loops handled inside gat_fused)
    hipMemsetAsync(cnt, 0, (size_t)N * 4, stream);
    count_rank_kernel<<<(E + 255) / 256, 256, 0, stream>>>(dstI, E, cnt, rank);
    scan_partial<<<NB, 256, 0, stream>>>(cnt, N, bsum);
    scan_bsums<<<1, 256, 0, stream>>>(bsum, NB, E, rowptr, N);
    scan_final<<<NB, 256, 0, stream>>>(cnt, N, bsum, rowptr);
    place_kernel<<<(E + 255) / 256, 256, 0, stream>>>(srcI, dstI, rank, E, rowptr, csr_src);

    const int GB = (N + 3) / 4;     // gat_fused blocks (4 nodes / 256-thread block)
    const int MB = (N + 63) / 64;   // gemm row-tiles (BM=64)

    // ---- layer 0 (din=128 f32, H=4, C=32, concat)
    {
        gemm_mfma<128, false><<<dim3(MB, 2), 256, 0, stream>>>(x, N, Bt0, bl[0], br[0], 128, xlbuf, xrbuf);
        gat_fused<4><<<GB, 256, 0, stream>>>(xlbuf, xrbuf, rowptr, csr_src, att[0], bb[0], hbuf, 128, N);
    }
    // ---- layer 1 (din=128 bf16)
    {
        gemm_mfma<128, true><<<dim3(MB, 2), 256, 0, stream>>>(hbuf, N, Bt1, bl[1], br[1], 128, xlbuf, xrbuf);
        gat_fused<4><<<GB, 256, 0, stream>>>(xlbuf, xrbuf, rowptr, csr_src, att[1], bb[1], hbuf, 128, N);
    }
    // ---- layer 2 (H=1, concat=False -> mean over 1 head = identity)
    {
        gemm_mfma<64, true><<<dim3(MB, 1), 256, 0, stream>>>(hbuf, N, Bt2, bl[2], br[2], 32, xlbuf, xrbuf);
        gat_fused<1><<<GB, 256, 0, stream>>>(xlbuf, xrbuf, rowptr, csr_src, att[2], bb[2], hbuf, 32, N);
    }
    // ---- fused global mean pool + head (batch sorted -> binary search, no atomics)
    pool_head_kernel<<<B, 128, 0, stream>>>(hbuf, 32, batch, N, meta, Wh1, bh1, Wh2, bh2, out);
}

// Round 16
// 376.896 us; speedup vs baseline: 1.0868x; 1.0223x over previous
//
#include <hip/hip_runtime.h>
#include <cstdint>
#include <cstddef>

#define NEG_SLOPE 0.2f
#define LOG2E 1.44269504f

typedef __attribute__((ext_vector_type(8))) short short8;   // 8 bf16 (4 VGPRs)
typedef __attribute__((ext_vector_type(4))) float f32x4;    // MFMA accumulator

__device__ __forceinline__ float bf2f(unsigned short u) {
    union { unsigned int i; float f; } x; x.i = ((unsigned int)u) << 16; return x.f;
}
__device__ __forceinline__ unsigned short f2bf(float f) {
    union { float f; unsigned int i; } x;
    x.f = f;
    unsigned int u = x.i;
    return (unsigned short)((u + 0x7FFFu + ((u >> 16) & 1u)) >> 16);   // RNE
}

// 8-lane sum via DPP (VALU pipe, no ds_bpermute): xor1, xor2 quad_perms,
// then row_half_mirror picks up the other quad's sum. Requires the 8-lane
// group to be lane-aligned to 8 and uniformly active (true here).
__device__ __forceinline__ float dpp_sum8(float p) {
    p += __int_as_float(__builtin_amdgcn_update_dpp(0, __float_as_int(p), 0xB1, 0xF, 0xF, true));  // quad_perm [1,0,3,2]
    p += __int_as_float(__builtin_amdgcn_update_dpp(0, __float_as_int(p), 0x4E, 0xF, 0xF, true));  // quad_perm [2,3,0,1]
    p += __int_as_float(__builtin_amdgcn_update_dpp(0, __float_as_int(p), 0x141, 0xF, 0xF, true)); // row_half_mirror
    return p;
}

// =====================================================================
// Weight prep (all 3 layers in one launch):
// Bt[n][k] = bf16([Wl | Wr][k][n]); layer0/1: dout=128, layer2: dout=32.
// =====================================================================
__global__ __launch_bounds__(256) void prep_w_all(
    const float* __restrict__ Wl0, const float* __restrict__ Wr0,
    const float* __restrict__ Wl1, const float* __restrict__ Wr1,
    const float* __restrict__ Wl2, const float* __restrict__ Wr2,
    unsigned short* __restrict__ Bt0, unsigned short* __restrict__ Bt1,
    unsigned short* __restrict__ Bt2)
{
    int idx = blockIdx.x * 256 + threadIdx.x;
    const int SZ = 256 * 128;     // layer0/1 table elems
    const float *Wl, *Wr; unsigned short* Bt; int dout;
    if (idx < SZ)              { Wl = Wl0; Wr = Wr0; Bt = Bt0; dout = 128; }
    else if (idx < 2 * SZ)     { Wl = Wl1; Wr = Wr1; Bt = Bt1; dout = 128; idx -= SZ; }
    else if (idx < 2 * SZ + 64 * 128) { Wl = Wl2; Wr = Wr2; Bt = Bt2; dout = 32; idx -= 2 * SZ; }
    else return;
    int n = idx >> 7, k = idx & 127;
    float v = (n < dout) ? Wl[(size_t)k * dout + n] : Wr[(size_t)k * dout + (n - dout)];
    Bt[idx] = f2bf(v);
}

// =====================================================================
// MFMA GEMM (LDS-staged): XL(bf16) | XR(bf16) = A[M x 128] @ Bt^T + b.
// Block = 64 rows x BN cols, 256 threads (4 waves). (r15 config.)
// =====================================================================
template<int BN, bool ABF16>
__global__ __launch_bounds__(256) void gemm_mfma(
    const void* __restrict__ Avoid, int M,
    const unsigned short* __restrict__ Bt,
    const float* __restrict__ bl, const float* __restrict__ br,
    int dout, unsigned short* __restrict__ XL, unsigned short* __restrict__ XR)
{
    constexpr int LDA = 136;                       // shorts; pad 128+8
    constexpr int NT  = BN / 16;
    __shared__ __attribute__((aligned(16))) unsigned short As[64 * LDA];
    __shared__ __attribute__((aligned(16))) unsigned short Bs[BN * LDA];
    const int t  = threadIdx.x;
    const int m0 = blockIdx.x * 64;
    const int n0 = blockIdx.y * BN;

    // ---- stage A (64 x 128 -> bf16 LDS), coalesced
    if (ABF16) {
        const unsigned short* A = (const unsigned short*)Avoid;
#pragma unroll
        for (int i = 0; i < 8; ++i) {
            int c   = t + i * 256;         // ushort4 chunks, [0, 2048)
            int row = c >> 5;              // 32 chunks per row
            int col = (c & 31) * 4;
            int gr  = m0 + row;
            ushort4 v = make_ushort4(0, 0, 0, 0);
            if (gr < M) v = *(const ushort4*)(A + (size_t)gr * 128 + col);
            *(ushort4*)(As + row * LDA + col) = v;
        }
    } else {
        const float* A = (const float*)Avoid;
#pragma unroll
        for (int i = 0; i < 8; ++i) {
            int c   = t + i * 256;         // float4 chunks, [0, 2048)
            int row = c >> 5;
            int col = (c & 31) * 4;
            int gr  = m0 + row;
            float4 v = make_float4(0.f, 0.f, 0.f, 0.f);
            if (gr < M) v = *(const float4*)(A + (size_t)gr * 128 + col);
            ushort4 o;
            o.x = f2bf(v.x); o.y = f2bf(v.y); o.z = f2bf(v.z); o.w = f2bf(v.w);
            *(ushort4*)(As + row * LDA + col) = o;
        }
    }
    // ---- stage B (BN x 128 bf16), coalesced
#pragma unroll
    for (int i = 0; i < BN / 16; ++i) {
        int c  = t + i * 256;              // short8 chunks
        int n  = c >> 4;                   // 16 chunks per row
        int kc = (c & 15) * 8;
        *(short8*)(Bs + n * LDA + kc) =
            *(const short8*)(Bt + (size_t)(n0 + n) * 128 + kc);
    }
    __syncthreads();

    const int w    = t >> 6;
    const int lane = t & 63;
    const int fr   = lane & 15;
    const int quad = lane >> 4;

    f32x4 acc[NT] = {};
    const unsigned short* ap = As + (w * 16 + fr) * LDA + quad * 8;
    const unsigned short* bp = Bs + fr * LDA + quad * 8;
#pragma unroll
    for (int k0 = 0; k0 < 128; k0 += 32) {
        short8 afr = *(const short8*)(ap + k0);
#pragma unroll
        for (int j = 0; j < NT; ++j) {
            short8 bfr = *(const short8*)(bp + j * 16 * LDA + k0);
            acc[j] = __builtin_amdgcn_mfma_f32_16x16x32_bf16(afr, bfr, acc[j], 0, 0, 0);
        }
    }

    // ---- epilogue: +bias, bf16 stores into XL | XR
#pragma unroll
    for (int j = 0; j < NT; ++j) {
        int col = n0 + j * 16 + fr;
        float bias = (col < dout) ? bl[col] : br[col - dout];
#pragma unroll
        for (int r = 0; r < 4; ++r) {
            int row = m0 + w * 16 + quad * 4 + r;
            if (row < M) {
                unsigned short o = f2bf(acc[j][r] + bias);
                if (col < dout) XL[(size_t)row * dout + col] = o;
                else            XR[(size_t)row * dout + (col - dout)] = o;
            }
        }
    }
}

// =====================================================================
// CSR build over dst: count+rank -> 3-phase device scan -> place (no
// atomics in place; rank captured in count which already pays the RMW).
// =====================================================================
__global__ void count_rank_kernel(const int* __restrict__ dst, int E,
                                  int* __restrict__ cnt, unsigned short* __restrict__ rank)
{
    int e = blockIdx.x * blockDim.x + threadIdx.x;
    if (e < E) {
        int p = atomicAdd(&cnt[dst[e]], 1);
        rank[e] = (unsigned short)p;
    }
}

__global__ __launch_bounds__(256) void scan_partial(
    const int* __restrict__ cnt, int N, int* __restrict__ bsum)
{
    __shared__ int red[4];
    const int t = threadIdx.x;
    const int base = blockIdx.x * 2048;
    int s = 0;
#pragma unroll
    for (int i = 0; i < 8; ++i) {
        int idx = base + t + i * 256;
        if (idx < N) s += cnt[idx];
    }
#pragma unroll
    for (int off = 32; off >= 1; off >>= 1) s += __shfl_xor(s, off);
    if ((t & 63) == 0) red[t >> 6] = s;
    __syncthreads();
    if (t == 0) bsum[blockIdx.x] = red[0] + red[1] + red[2] + red[3];
}

__global__ __launch_bounds__(256) void scan_bsums(
    int* __restrict__ bsum, int nb, int E, int* __restrict__ rowptr, int N)
{
    __shared__ int sh[256];
    const int t = threadIdx.x;
    int v = (t < nb) ? bsum[t] : 0;
    sh[t] = v;
    __syncthreads();
    for (int off = 1; off < 256; off <<= 1) {
        int u = (t >= off) ? sh[t - off] : 0;
        __syncthreads();
        sh[t] += u;
        __syncthreads();
    }
    if (t < nb) bsum[t] = sh[t] - v;   // exclusive prefix
    if (t == 0) rowptr[N] = E;
}

__global__ __launch_bounds__(256) void scan_final(
    const int* __restrict__ cnt, int N, const int* __restrict__ bsum,
    int* __restrict__ rowptr)
{
    __shared__ int sdat[2048];
    __shared__ int tsum[256];
    const int t = threadIdx.x;
    const int base = blockIdx.x * 2048;
#pragma unroll
    for (int i = 0; i < 8; ++i) {
        int idx = base + t + i * 256;
        sdat[t + i * 256] = (idx < N) ? cnt[idx] : 0;
    }
    __syncthreads();
    int vals[8];
    int s = 0;
#pragma unroll
    for (int j = 0; j < 8; ++j) { vals[j] = sdat[t * 8 + j]; s += vals[j]; }
    tsum[t] = s;
    __syncthreads();
    for (int off = 1; off < 256; off <<= 1) {
        int u = (t >= off) ? tsum[t - off] : 0;
        __syncthreads();
        tsum[t] += u;
        __syncthreads();
    }
    int run = bsum[blockIdx.x] + tsum[t] - s;   // exclusive prefix of this chunk
#pragma unroll
    for (int j = 0; j < 8; ++j) { sdat[t * 8 + j] = run; run += vals[j]; }
    __syncthreads();
#pragma unroll
    for (int i = 0; i < 8; ++i) {
        int idx = base + t + i * 256;
        if (idx < N) rowptr[idx] = sdat[t + i * 256];
    }
}

__global__ void place_kernel(const int* __restrict__ src, const int* __restrict__ dst,
                             const unsigned short* __restrict__ rank, int E,
                             const int* __restrict__ rowptr,
                             unsigned short* __restrict__ csr_src)
{
    int e = blockIdx.x * blockDim.x + threadIdx.x;
    if (e < E)
        csr_src[rowptr[dst[e]] + rank[e]] = (unsigned short)src[e];
}

// =====================================================================
// Fused GATv2 edge phase — bf16 xl/xr tables, bf16 output, 4 ch/lane:
//   r12/r15-best structure, but the per-edge 8-lane logit reduce runs
//   on the VALU pipe via DPP (dpp_sum8) instead of ds_bpermute shfls —
//   the hot loop issues ZERO LDS-pipe ops. Node-level slot merges stay
//   shfl (once per node). Plain-sum exp2-domain softmax.
// =====================================================================
template<int H>
__global__ __launch_bounds__(256, 4) void gat_fused(
    const unsigned short* __restrict__ xl, const unsigned short* __restrict__ xr,
    const int* __restrict__ rowptr, const unsigned short* __restrict__ csr_src,
    const float* __restrict__ att, const float* __restrict__ bias,
    unsigned short* __restrict__ hout, int hstride, int N)
{
    constexpr int HC  = 32 * H;
    constexpr int LPE = HC / 4;      // lanes per edge (H=4: 32, H=1: 8)
    constexpr int EPW = 64 / LPE;    // edge slots per wave (2 / 8)
    const int node = blockIdx.x * 4 + (threadIdx.x >> 6);
    if (node >= N) return;
    const int lane = threadIdx.x & 63;
    const int q    = lane % LPE;
    const int slot = lane / LPE;
    const int rs   = rowptr[node];
    const int re   = rowptr[node + 1];

    const unsigned short* __restrict__ xlb = xl + 4 * q;
    float4 xri;
    {
        ushort4 u = *(const ushort4*)(xr + (size_t)node * HC + 4 * q);
        xri.x = bf2f(u.x); xri.y = bf2f(u.y); xri.z = bf2f(u.z); xri.w = bf2f(u.w);
    }
    float4 af = *(const float4*)(att + 4 * q);
    af.x *= LOG2E; af.y *= LOG2E; af.z *= LOG2E; af.w *= LOG2E;   // exp2 domain

    float l = 0.f;
    float4 acc = make_float4(0.f, 0.f, 0.f, 0.f);

    auto ld4 = [&](int s) -> float4 {
        ushort4 u = *(const ushort4*)(xlb + (size_t)s * HC);
        float4 v;
        v.x = bf2f(u.x); v.y = bf2f(u.y); v.z = bf2f(u.z); v.w = bf2f(u.w);
        return v;
    };

    auto edge_w = [&](const float4& v) -> float {   // exp2(att . leakyrelu(v+xri))
        float sx = v.x + xri.x, sy = v.y + xri.y, sz = v.z + xri.z, sw = v.w + xri.w;
        sx = fmaxf(sx, NEG_SLOPE * sx);
        sy = fmaxf(sy, NEG_SLOPE * sy);
        sz = fmaxf(sz, NEG_SLOPE * sz);
        sw = fmaxf(sw, NEG_SLOPE * sw);
        float p = af.x * sx;
        p = fmaf(af.y, sy, p);
        p = fmaf(af.z, sz, p);
        p = fmaf(af.w, sw, p);
        p = dpp_sum8(p);                 // 8-lane head reduce, VALU pipe
        return exp2f(p);
    };

    // ---- self-loop (src = dst = node), slot 0 only
    if (slot == 0) {
        float4 v = ld4(node);
        float w = edge_w(v);
        l = w;
        acc.x = w * v.x; acc.y = w * v.y; acc.z = w * v.z; acc.w = w * v.w;
    }

    // ---- incoming edges, strided per slot, unrolled x2 (no predication)
    int k = rs + slot;
    for (; k + EPW < re; k += 2 * EPW) {
        int s0 = csr_src[k];
        int s1 = csr_src[k + EPW];
        float4 v0 = ld4(s0);
        float4 v1 = ld4(s1);
        float w0 = edge_w(v0);
        float w1 = edge_w(v1);
        l += w0 + w1;
        acc.x = fmaf(w0, v0.x, fmaf(w1, v1.x, acc.x));
        acc.y = fmaf(w0, v0.y, fmaf(w1, v1.y, acc.y));
        acc.z = fmaf(w0, v0.z, fmaf(w1, v1.z, acc.z));
        acc.w = fmaf(w0, v0.w, fmaf(w1, v1.w, acc.w));
    }
    if (k < re) {
        int s0 = csr_src[k];
        float4 v0 = ld4(s0);
        float w0 = edge_w(v0);
        l += w0;
        acc.x = fmaf(w0, v0.x, acc.x);
        acc.y = fmaf(w0, v0.y, acc.y);
        acc.z = fmaf(w0, v0.z, acc.z);
        acc.w = fmaf(w0, v0.w, acc.w);
    }

    // ---- merge edge slots: plain sums (once per node)
#pragma unroll
    for (int mask = LPE; mask < 64; mask <<= 1) {
        l     += __shfl_xor(l, mask);
        acc.x += __shfl_xor(acc.x, mask);
        acc.y += __shfl_xor(acc.y, mask);
        acc.z += __shfl_xor(acc.z, mask);
        acc.w += __shfl_xor(acc.w, mask);
    }

    if (lane < LPE) {
        const float4 bi = *(const float4*)(bias + 4 * q);
        float inv = 1.f / (l + 1e-16f);
        float4 o;
        o.x = acc.x * inv + bi.x;
        o.y = acc.y * inv + bi.y;
        o.z = acc.z * inv + bi.z;
        o.w = acc.w * inv + bi.w;
        o.x = (o.x > 0.f) ? o.x : expm1f(o.x);
        o.y = (o.y > 0.f) ? o.y : expm1f(o.y);
        o.z = (o.z > 0.f) ? o.z : expm1f(o.z);
        o.w = (o.w > 0.f) ? o.w : expm1f(o.w);
        ushort4 ob;
        ob.x = f2bf(o.x); ob.y = f2bf(o.y); ob.z = f2bf(o.z); ob.w = f2bf(o.w);
        *(ushort4*)(hout + (size_t)node * hstride + 4 * q) = ob;
    }
}

// =====================================================================
// Fused mean-pool + MLP head (h is bf16). One block per graph; batch is
// SORTED so graph b's nodes are rows [lower_bound(b), lower_bound(b+1)).
// =====================================================================
__global__ __launch_bounds__(128) void pool_head_kernel(
    const unsigned short* __restrict__ h, int hstride,
    const int* __restrict__ batch, int N,
    const float* __restrict__ meta,
    const float* __restrict__ Wh1, const float* __restrict__ bh1,
    const float* __restrict__ Wh2, const float* __restrict__ bh2,
    float* __restrict__ out)
{
    const int b = blockIdx.x;
    const int t = threadIdx.x;
    __shared__ float s[128];
    __shared__ float z[44];

    int lo = 0, hi = N;
    while (lo < hi) { int mid = (lo + hi) >> 1; if (batch[mid] < b) lo = mid + 1; else hi = mid; }
    int lo2 = lo, hi2 = N;
    while (lo2 < hi2) { int mid = (lo2 + hi2) >> 1; if (batch[mid] < b + 1) lo2 = mid + 1; else hi2 = mid; }
    const int start = lo, end = lo2;

    const int c = t & 31, r = t >> 5;     // 4 rows x 32 channels in flight
    float acc = 0.f;
    for (int row = start + r; row < end; row += 4)
        acc += bf2f(h[(size_t)row * hstride + c]);
    s[t] = acc;
    __syncthreads();
    if (t < 32) {
        float sum = s[t] + s[t + 32] + s[t + 64] + s[t + 96];
        z[t] = sum / fmaxf((float)(end - start), 1.0f);
    } else if (t < 44) {
        z[t] = meta[(size_t)b * 12 + (t - 32)];
    }
    __syncthreads();
    if (t < 32) {
        float hj = bh1[t];
#pragma unroll
        for (int k = 0; k < 44; ++k)
            hj = fmaf(z[k], Wh1[k * 32 + t], hj);
        hj = fmaxf(hj, 0.f);
        float p = hj * Wh2[t];
#pragma unroll
        for (int off = 16; off >= 1; off >>= 1)
            p += __shfl_xor(p, off, 32);
        if (t == 0) out[b] = p + bh2[0];
    }
}

// =====================================================================
extern "C" void kernel_launch(void* const* d_in, const int* in_sizes, int n_in,
                              void* d_out, int out_size, void* d_ws, size_t ws_size,
                              hipStream_t stream)
{
    const float* x     = (const float*)d_in[0];
    const int*   ei    = (const int*)d_in[1];
    const int*   batch = (const int*)d_in[2];
    const float* meta  = (const float*)d_in[3];
    const float* Wl[3]  = {(const float*)d_in[4],  (const float*)d_in[10], (const float*)d_in[16]};
    const float* bl[3]  = {(const float*)d_in[5],  (const float*)d_in[11], (const float*)d_in[17]};
    const float* Wr[3]  = {(const float*)d_in[6],  (const float*)d_in[12], (const float*)d_in[18]};
    const float* br[3]  = {(const float*)d_in[7],  (const float*)d_in[13], (const float*)d_in[19]};
    const float* att[3] = {(const float*)d_in[8],  (const float*)d_in[14], (const float*)d_in[20]};
    const float* bb[3]  = {(const float*)d_in[9],  (const float*)d_in[15], (const float*)d_in[21]};
    const float* Wh1 = (const float*)d_in[22];
    const float* bh1 = (const float*)d_in[23];
    const float* Wh2 = (const float*)d_in[24];
    const float* bh2 = (const float*)d_in[25];
    float* out = (float*)d_out;

    const int N  = in_sizes[0] / 128;
    const int E  = in_sizes[1] / 2;
    const int B  = in_sizes[3] / 12;
    const int NB = (N + 2047) / 2048;   // scan tiles (<= 256)

    char* wsp = (char*)d_ws;
    size_t off_ = 0;
    auto alloc = [&](size_t bytes) {
        char* p = wsp + off_;
        off_ = (off_ + bytes + 255) & ~(size_t)255;
        return p;
    };
    unsigned short* xlbuf = (unsigned short*)alloc((size_t)N * 128 * 2);  // bf16 gather table
    unsigned short* xrbuf = (unsigned short*)alloc((size_t)N * 128 * 2);  // bf16 xr table
    unsigned short* hbuf  = (unsigned short*)alloc((size_t)N * 128 * 2);  // bf16 layer output
    int*   cnt     = (int*)alloc((size_t)N * 4);
    int*   rowptr  = (int*)alloc((size_t)(N + 1) * 4);
    unsigned short* rank    = (unsigned short*)alloc((size_t)E * 2);  // rank within dst bucket
    unsigned short* csr_src = (unsigned short*)alloc((size_t)E * 2);  // src < 65536
    unsigned short* Bt0     = (unsigned short*)alloc((size_t)256 * 128 * 2);
    unsigned short* Bt1     = (unsigned short*)alloc((size_t)256 * 128 * 2);
    unsigned short* Bt2     = (unsigned short*)alloc((size_t)64 * 128 * 2);
    int*   bsum    = (int*)alloc((size_t)256 * 4);

    const int* srcI = ei;
    const int* dstI = ei + E;

    // ---- weight prep (independent of everything else)
    prep_w_all<<<(2 * 256 * 128 + 64 * 128 + 255) / 256, 256, 0, stream>>>(
        Wl[0], Wr[0], Wl[1], Wr[1], Wl[2], Wr[2], Bt0, Bt1, Bt2);

    // ---- CSR over dst (real edges; self-loops handled inside gat_fused)
    hipMemsetAsync(cnt, 0, (size_t)N * 4, stream);
    count_rank_kernel<<<(E + 255) / 256, 256, 0, stream>>>(dstI, E, cnt, rank);
    scan_partial<<<NB, 256, 0, stream>>>(cnt, N, bsum);
    scan_bsums<<<1, 256, 0, stream>>>(bsum, NB, E, rowptr, N);
    scan_final<<<NB, 256, 0, stream>>>(cnt, N, bsum, rowptr);
    place_kernel<<<(E + 255) / 256, 256, 0, stream>>>(srcI, dstI, rank, E, rowptr, csr_src);

    const int GB = (N + 3) / 4;     // gat_fused blocks (4 nodes / 256-thread block)
    const int MB = (N + 63) / 64;   // gemm row-tiles (BM=64)

    // ---- layer 0 (din=128 f32, H=4, C=32, concat)
    {
        gemm_mfma<128, false><<<dim3(MB, 2), 256, 0, stream>>>(x, N, Bt0, bl[0], br[0], 128, xlbuf, xrbuf);
        gat_fused<4><<<GB, 256, 0, stream>>>(xlbuf, xrbuf, rowptr, csr_src, att[0], bb[0], hbuf, 128, N);
    }
    // ---- layer 1 (din=128 bf16)
    {
        gemm_mfma<128, true><<<dim3(MB, 2), 256, 0, stream>>>(hbuf, N, Bt1, bl[1], br[1], 128, xlbuf, xrbuf);
        gat_fused<4><<<GB, 256, 0, stream>>>(xlbuf, xrbuf, rowptr, csr_src, att[1], bb[1], hbuf, 128, N);
    }
    // ---- layer 2 (H=1, concat=False -> mean over 1 head = identity)
    {
        gemm_mfma<64, true><<<dim3(MB, 1), 256, 0, stream>>>(hbuf, N, Bt2, bl[2], br[2], 32, xlbuf, xrbuf);
        gat_fused<1><<<GB, 256, 0, stream>>>(xlbuf, xrbuf, rowptr, csr_src, att[2], bb[2], hbuf, 32, N);
    }
    // ---- fused global mean pool + head (batch sorted -> binary search, no atomics)
    pool_head_kernel<<<B, 128, 0, stream>>>(hbuf, 32, batch, N, meta, Wh1, bh1, Wh2, bh2, out);
}